// Round 2
// baseline (260.005 us; speedup 1.0000x reference)
//
#include <hip/hip_runtime.h>
#include <stdint.h>

typedef unsigned int u32;
typedef unsigned long long u64;

#define NW      147456   // 128*128*9
#define HW      3136     // 56*56
#define PADW    58

// ---------------------------------------------------------------------------
// Kernel 1: weight synthesis + sign-pack. sign(w) = sign(m + rv.z).
// One block per output channel o. Phase 1: coalesced float4 loads of the
// 1152-float (i,kh,kw) slice of M and the 5 Z's, fused FMA, stage to LDS.
// Phase 2: 36 threads assemble bit-words: wb[(o*9+tap)*4 + wd], bit = ch%32.
__global__ __launch_bounds__(256) void k_wsynth(
    const float* __restrict__ M, const float* __restrict__ Z,
    const float* __restrict__ rv, u32* __restrict__ wb)
{
  __shared__ float sw[1152];
  int o = blockIdx.x;
  int t = threadIdx.x;
  float r0 = rv[0], r1 = rv[1], r2 = rv[2], r3 = rv[3], r4 = rv[4];
  const float4* M4 = (const float4*)M;
  const float4* Z4 = (const float4*)Z;
  float4* sw4 = (float4*)sw;

  for (int j = t; j < 288; j += 256) {
    float4 a = M4[o * 288 + j];
    float4 z;
    z = Z4[0 * 36864 + o * 288 + j];
    a.x = fmaf(r0, z.x, a.x); a.y = fmaf(r0, z.y, a.y);
    a.z = fmaf(r0, z.z, a.z); a.w = fmaf(r0, z.w, a.w);
    z = Z4[1 * 36864 + o * 288 + j];
    a.x = fmaf(r1, z.x, a.x); a.y = fmaf(r1, z.y, a.y);
    a.z = fmaf(r1, z.z, a.z); a.w = fmaf(r1, z.w, a.w);
    z = Z4[2 * 36864 + o * 288 + j];
    a.x = fmaf(r2, z.x, a.x); a.y = fmaf(r2, z.y, a.y);
    a.z = fmaf(r2, z.z, a.z); a.w = fmaf(r2, z.w, a.w);
    z = Z4[3 * 36864 + o * 288 + j];
    a.x = fmaf(r3, z.x, a.x); a.y = fmaf(r3, z.y, a.y);
    a.z = fmaf(r3, z.z, a.z); a.w = fmaf(r3, z.w, a.w);
    z = Z4[4 * 36864 + o * 288 + j];
    a.x = fmaf(r4, z.x, a.x); a.y = fmaf(r4, z.y, a.y);
    a.z = fmaf(r4, z.z, a.z); a.w = fmaf(r4, z.w, a.w);
    sw4[j] = a;
  }
  __syncthreads();

  if (t < 36) {
    int tap = t >> 2;
    int wd  = t & 3;
    u32 bits = 0;
#pragma unroll
    for (int c = 0; c < 32; ++c) {
      float v = sw[(wd * 32 + c) * 9 + tap];
      bits |= (v > 0.0f ? 1u : 0u) << c;
    }
    wb[(o * 9 + tap) * 4 + wd] = bits;
  }
}

// ---------------------------------------------------------------------------
// Kernel 2: activation sign-pack, coalesced. Block = (b, 4-row group).
// 4 rows x 56 w = 224 contiguous floats per channel; thread = 1 pixel,
// loops all 128 channels accumulating its 128-bit word in registers.
__global__ __launch_bounds__(256) void k_apack(
    const float* __restrict__ x, uint4* __restrict__ ab)
{
  int t  = threadIdx.x;
  if (t >= 224) return;
  int rg = blockIdx.x % 14;
  int b  = blockIdx.x / 14;
  int h  = rg * 4 + t / 56;
  int w  = t % 56;
  const float* xp = x + (size_t)b * (128 * HW) + (size_t)(rg * 4) * 56 + t;

  u32 w0 = 0, w1 = 0, w2 = 0, w3 = 0;
#pragma unroll 8
  for (int c = 0; c < 32; ++c) {
    w0 |= (xp[(size_t)(c      ) * HW] > 0.0f ? 1u : 0u) << c;
    w1 |= (xp[(size_t)(c +  32) * HW] > 0.0f ? 1u : 0u) << c;
    w2 |= (xp[(size_t)(c +  64) * HW] > 0.0f ? 1u : 0u) << c;
    w3 |= (xp[(size_t)(c +  96) * HW] > 0.0f ? 1u : 0u) << c;
  }
  ab[((size_t)b * PADW + (h + 1)) * PADW + (w + 1)] = make_uint4(w0, w1, w2, w3);
}

// ---------------------------------------------------------------------------
// Kernel 3a: interior conv (h,w in [1,54]) — all 9 taps valid, no masks.
// out = (1152 - 2*popc(a^w)) * alpha. Weights read via wave-uniform global
// loads (scalar-cache path). blockIdx.y selects a 32-wide o-group.
__global__ __launch_bounds__(256) void k_conv_int(
    const uint4* __restrict__ ab, const uint4* __restrict__ wbg,
    const float* __restrict__ Alpha, float* __restrict__ out)
{
  int p = blockIdx.x * 256 + threadIdx.x;
  if (p >= 32 * 54 * 54) return;
  int b = p / 2916;
  int r = p - b * 2916;
  int h = 1 + r / 54;
  int w = 1 + r - (r / 54) * 54;

  const uint4* abp = ab + ((size_t)b * PADW + h) * PADW + w;  // tap (0,0)
  u32 a[9][4];
#pragma unroll
  for (int dh = 0; dh < 3; ++dh)
#pragma unroll
    for (int dw = 0; dw < 3; ++dw) {
      uint4 v = abp[(size_t)dh * PADW + dw];
      int tt = dh * 3 + dw;
      a[tt][0] = v.x; a[tt][1] = v.y; a[tt][2] = v.z; a[tt][3] = v.w;
    }

  int og = blockIdx.y;
  float* outp = out + ((size_t)b * 128 + og * 32) * HW + h * 56 + w;
#pragma unroll 2
  for (int oi = 0; oi < 32; ++oi) {
    int o = og * 32 + oi;
    int s = 0;
#pragma unroll
    for (int tt = 0; tt < 9; ++tt) {
      uint4 wv = wbg[o * 9 + tt];
      s += __popc(a[tt][0] ^ wv.x);
      s += __popc(a[tt][1] ^ wv.y);
      s += __popc(a[tt][2] ^ wv.z);
      s += __popc(a[tt][3] ^ wv.w);
    }
    outp[(size_t)oi * HW] = (float)(1152 - 2 * s) * Alpha[o];
  }
}

// ---------------------------------------------------------------------------
// Kernel 3b: border pixels (220 per image), masked path, all 128 o's.
__global__ __launch_bounds__(256) void k_conv_border(
    const uint4* __restrict__ ab, const uint4* __restrict__ wbg,
    const float* __restrict__ Alpha, float* __restrict__ out)
{
  int p = blockIdx.x * 256 + threadIdx.x;
  if (p >= 32 * 220) return;
  int b = p / 220;
  int e = p - b * 220;
  int h, w;
  if      (e < 56)  { h = 0;  w = e; }
  else if (e < 112) { h = 55; w = e - 56; }
  else if (e < 166) { w = 0;  h = e - 112 + 1; }
  else              { w = 55; h = e - 166 + 1; }

  u32 a[9][4];
  u32 kk[9];
  int nv = 0;
#pragma unroll
  for (int dh = 0; dh < 3; ++dh)
#pragma unroll
    for (int dw = 0; dw < 3; ++dw) {
      int tt = dh * 3 + dw;
      int hh = h + dh;   // padded coords
      int ww = w + dw;
      uint4 v = ab[((size_t)b * PADW + hh) * PADW + ww];
      a[tt][0] = v.x; a[tt][1] = v.y; a[tt][2] = v.z; a[tt][3] = v.w;
      int valid = (hh >= 1) & (hh <= 56) & (ww >= 1) & (ww <= 56);
      kk[tt] = valid ? 0xffffffffu : 0u;
      nv += valid;
    }
  int base = nv * 128;
  float* outp = out + (size_t)b * (128 * HW) + h * 56 + w;

  for (int o = 0; o < 128; ++o) {
    int s = 0;
#pragma unroll
    for (int tt = 0; tt < 9; ++tt) {
      uint4 wv = wbg[o * 9 + tt];
      s += __popc((a[tt][0] ^ wv.x) & kk[tt]);
      s += __popc((a[tt][1] ^ wv.y) & kk[tt]);
      s += __popc((a[tt][2] ^ wv.z) & kk[tt]);
      s += __popc((a[tt][3] ^ wv.w) & kk[tt]);
    }
    outp[(size_t)o * HW] = (float)(base - 2 * s) * Alpha[o];
  }
}

// ---------------------------------------------------------------------------
extern "C" void kernel_launch(void* const* d_in, const int* in_sizes, int n_in,
                              void* d_out, int out_size, void* d_ws, size_t ws_size,
                              hipStream_t stream)
{
  const float* x     = (const float*)d_in[0];
  const float* Alpha = (const float*)d_in[1];
  const float* M     = (const float*)d_in[2];
  const float* Z     = (const float*)d_in[3];
  const float* rv    = (const float*)d_in[4];
  float* out         = (float*)d_out;

  u32*   wb = (u32*)d_ws;                            // 4608 u32 = 18432 B
  uint4* ab = (uint4*)((char*)d_ws + 18432);         // 32*58*58 uint4

  hipMemsetAsync(ab, 0, (size_t)32 * PADW * PADW * sizeof(uint4), stream);

  k_wsynth<<<128, 256, 0, stream>>>(M, Z, rv, wb);
  k_apack<<<32 * 14, 256, 0, stream>>>(x, ab);
  dim3 gi((32 * 54 * 54 + 255) / 256, 4);
  k_conv_int<<<gi, 256, 0, stream>>>(ab, (const uint4*)wb, Alpha, out);
  k_conv_border<<<(32 * 220 + 255) / 256, 256, 0, stream>>>(ab, (const uint4*)wb, Alpha, out);
}

// Round 3
// 147.400 us; speedup vs baseline: 1.7639x; 1.7639x over previous
//
#include <hip/hip_runtime.h>
#include <stdint.h>

typedef unsigned int u32;
typedef unsigned long long u64;

#define NW      147456   // 128*128*9
#define HW      3136     // 56*56
#define PADW    58
#define PADHW   3364     // 58*58

#define NBI     365      // interior pixel-blocks per o-group: ceil(32*54*54/256)
#define NOG     8        // interior o-groups (16 o's each)
#define NBB     440      // border blocks: 16 og * 32 b * 220 e / 256

// ---------------------------------------------------------------------------
// Kernel 1: weight synthesis + sign-pack. sign(w) = sign(m + rv.z) since the
// rsqrt normalizer is positive. One block per o; coalesced float4 loads,
// LDS stage, 36 threads assemble bits: wb[(o*9+tap)*4+wd], bit = ch%32.
__global__ __launch_bounds__(256) void k_wsynth(
    const float* __restrict__ M, const float* __restrict__ Z,
    const float* __restrict__ rv, u32* __restrict__ wb)
{
  __shared__ float sw[1152];
  int o = blockIdx.x;
  int t = threadIdx.x;
  float r0 = rv[0], r1 = rv[1], r2 = rv[2], r3 = rv[3], r4 = rv[4];
  const float4* M4 = (const float4*)M;
  const float4* Z4 = (const float4*)Z;
  float4* sw4 = (float4*)sw;

  for (int j = t; j < 288; j += 256) {
    float4 a = M4[o * 288 + j];
    float4 z;
    z = Z4[0 * 36864 + o * 288 + j];
    a.x = fmaf(r0, z.x, a.x); a.y = fmaf(r0, z.y, a.y);
    a.z = fmaf(r0, z.z, a.z); a.w = fmaf(r0, z.w, a.w);
    z = Z4[1 * 36864 + o * 288 + j];
    a.x = fmaf(r1, z.x, a.x); a.y = fmaf(r1, z.y, a.y);
    a.z = fmaf(r1, z.z, a.z); a.w = fmaf(r1, z.w, a.w);
    z = Z4[2 * 36864 + o * 288 + j];
    a.x = fmaf(r2, z.x, a.x); a.y = fmaf(r2, z.y, a.y);
    a.z = fmaf(r2, z.z, a.z); a.w = fmaf(r2, z.w, a.w);
    z = Z4[3 * 36864 + o * 288 + j];
    a.x = fmaf(r3, z.x, a.x); a.y = fmaf(r3, z.y, a.y);
    a.z = fmaf(r3, z.z, a.z); a.w = fmaf(r3, z.w, a.w);
    z = Z4[4 * 36864 + o * 288 + j];
    a.x = fmaf(r4, z.x, a.x); a.y = fmaf(r4, z.y, a.y);
    a.z = fmaf(r4, z.z, a.z); a.w = fmaf(r4, z.w, a.w);
    sw4[j] = a;
  }
  __syncthreads();

  if (t < 36) {
    int tap = t >> 2;
    int wd  = t & 3;
    u32 bits = 0;
#pragma unroll
    for (int c = 0; c < 32; ++c) {
      float v = sw[(wd * 32 + c) * 9 + tap];
      bits |= (v > 0.0f ? 1u : 0u) << c;
    }
    wb[(o * 9 + tap) * 4 + wd] = bits;
  }
}

// ---------------------------------------------------------------------------
// Kernel 2: activation sign-pack into padded 58x58 bit array, writing the
// zero ring itself (no memset). Thread = (padded pixel, 32-ch group).
// Wave = 64 consecutive padded pixels, one group -> coalesced x reads.
__global__ __launch_bounds__(256) void k_apack(
    const float* __restrict__ x, u32* __restrict__ abw)
{
  int t     = threadIdx.x;
  int chunk = blockIdx.x % 53;         // 53 * 64 = 3392 >= 3364 padded px
  int b     = blockIdx.x / 53;
  int px    = chunk * 64 + (t & 63);   // padded pixel 0..3363
  int g     = t >> 6;                  // channel group 0..3
  if (px >= PADHW) return;
  int ph = px / PADW;
  int pw = px - ph * PADW;
  u32 bits = 0;
  if (ph >= 1 && ph <= 56 && pw >= 1 && pw <= 56) {
    const float* xp = x + (size_t)b * (128 * HW) + (size_t)g * (32 * HW)
                        + (ph - 1) * 56 + (pw - 1);
#pragma unroll
    for (int c = 0; c < 32; ++c)
      bits |= (xp[(size_t)c * HW] > 0.0f ? 1u : 0u) << c;
  }
  abw[((size_t)b * PADHW + px) * 4 + g] = bits;
}

// ---------------------------------------------------------------------------
// Kernel 3: fused popcount conv. Blocks [0, NBI*NOG): interior (maskless,
// 16 o's/thread). Blocks [NBI*NOG, +NBB): border (masked, 8 o's/thread).
// Weight/alpha indices are wave-uniform -> scalar-cache loads.
__global__ __launch_bounds__(256) void k_conv(
    const uint4* __restrict__ ab, const uint4* __restrict__ wbg,
    const float* __restrict__ Alpha, float* __restrict__ out)
{
  int bx  = blockIdx.x;
  int tid = threadIdx.x;

  if (bx < NBI * NOG) {
    // ---- interior: h,w in [1,54], all 9 taps valid ----
    int og = bx / NBI;
    int bp = bx - og * NBI;
    int p  = bp * 256 + tid;
    if (p >= 32 * 54 * 54) return;
    int b = p / 2916;
    int r = p - b * 2916;
    int h = 1 + r / 54;
    int w = 1 + (r - (r / 54) * 54);

    const uint4* abp = ab + ((size_t)b * PADW + h) * PADW + w;
    u32 a[9][4];
#pragma unroll
    for (int dh = 0; dh < 3; ++dh)
#pragma unroll
      for (int dw = 0; dw < 3; ++dw) {
        uint4 v = abp[(size_t)dh * PADW + dw];
        int tt = dh * 3 + dw;
        a[tt][0] = v.x; a[tt][1] = v.y; a[tt][2] = v.z; a[tt][3] = v.w;
      }

    float* outp = out + ((size_t)b * 128 + og * 16) * HW + h * 56 + w;
#pragma unroll 2
    for (int oi = 0; oi < 16; ++oi) {
      int o = og * 16 + oi;
      int s = 0;
#pragma unroll
      for (int tt = 0; tt < 9; ++tt) {
        uint4 wv = wbg[o * 9 + tt];
        s += __popc(a[tt][0] ^ wv.x);
        s += __popc(a[tt][1] ^ wv.y);
        s += __popc(a[tt][2] ^ wv.z);
        s += __popc(a[tt][3] ^ wv.w);
      }
      outp[(size_t)oi * HW] = (float)(1152 - 2 * s) * Alpha[o];
    }
  } else {
    // ---- border: 220 ring pixels per image, masked taps ----
    int idx = (bx - NBI * NOG) * 256 + tid;   // = og*7040 + b*220 + e
    int og  = idx / 7040;                     // 0..15 (8 o's each)
    int rem = idx - og * 7040;
    int b   = rem / 220;
    int e   = rem - b * 220;
    int h, w;
    if      (e < 56)  { h = 0;  w = e; }
    else if (e < 112) { h = 55; w = e - 56; }
    else if (e < 166) { w = 0;  h = e - 111; }
    else              { w = 55; h = e - 165; }

    u32 a[9][4];
    u32 kk[9];
    int nv = 0;
#pragma unroll
    for (int dh = 0; dh < 3; ++dh)
#pragma unroll
      for (int dw = 0; dw < 3; ++dw) {
        int tt = dh * 3 + dw;
        int hh = h + dh;
        int ww = w + dw;
        uint4 v = ab[((size_t)b * PADW + hh) * PADW + ww];
        a[tt][0] = v.x; a[tt][1] = v.y; a[tt][2] = v.z; a[tt][3] = v.w;
        int valid = (hh >= 1) & (hh <= 56) & (ww >= 1) & (ww <= 56);
        kk[tt] = valid ? 0xffffffffu : 0u;
        nv += valid;
      }
    int base = nv * 128;
    float* outp = out + ((size_t)b * 128 + og * 8) * HW + h * 56 + w;

#pragma unroll 2
    for (int oi = 0; oi < 8; ++oi) {
      int o = og * 8 + oi;
      int s = 0;
#pragma unroll
      for (int tt = 0; tt < 9; ++tt) {
        uint4 wv = wbg[o * 9 + tt];
        s += __popc((a[tt][0] ^ wv.x) & kk[tt]);
        s += __popc((a[tt][1] ^ wv.y) & kk[tt]);
        s += __popc((a[tt][2] ^ wv.z) & kk[tt]);
        s += __popc((a[tt][3] ^ wv.w) & kk[tt]);
      }
      outp[(size_t)oi * HW] = (float)(base - 2 * s) * Alpha[o];
    }
  }
}

// ---------------------------------------------------------------------------
extern "C" void kernel_launch(void* const* d_in, const int* in_sizes, int n_in,
                              void* d_out, int out_size, void* d_ws, size_t ws_size,
                              hipStream_t stream)
{
  const float* x     = (const float*)d_in[0];
  const float* Alpha = (const float*)d_in[1];
  const float* M     = (const float*)d_in[2];
  const float* Z     = (const float*)d_in[3];
  const float* rv    = (const float*)d_in[4];
  float* out         = (float*)d_out;

  u32* wb = (u32*)d_ws;                       // 4608 u32 = 18432 B
  u32* ab = (u32*)((char*)d_ws + 18432);      // 32*3364 uint4

  k_wsynth<<<128, 256, 0, stream>>>(M, Z, rv, wb);
  k_apack<<<32 * 53, 256, 0, stream>>>(x, ab);
  k_conv<<<NBI * NOG + NBB, 256, 0, stream>>>((const uint4*)ab, (const uint4*)wb, Alpha, out);
}

// Round 4
// 136.454 us; speedup vs baseline: 1.9054x; 1.0802x over previous
//
#include <hip/hip_runtime.h>
#include <stdint.h>

typedef unsigned int u32;
typedef unsigned long long u64;

#define HW      3136     // 56*56
#define PADW    58
#define PADHW   3364     // 58*58

// d_ws layout
#define WB_OFF   0        // 4608 u32  (18432 B)  packed weights
#define BF_OFF   18432    // 9*128 f32 (4608 B)   per-(class,o) base, alpha-folded
#define N2A_OFF  23040    // 128 f32   (512 B)    -2*alpha
#define AB_OFF   23552    // 32*3364 uint4        padded activation bits

// ---------------------------------------------------------------------------
// Prep kernel. Blocks [0,128): weight synthesis + sign-pack + correction
// tables (sign(w) = sign(m + rv.z); rsqrt normalizer positive). Blocks
// [128,128+1696): activation sign-pack into zero-ringed padded bit array.
__global__ __launch_bounds__(256) void k_prep(
    const float* __restrict__ x, const float* __restrict__ Alpha,
    const float* __restrict__ M, const float* __restrict__ Z,
    const float* __restrict__ rv, char* __restrict__ ws)
{
  int t = threadIdx.x;
  if (blockIdx.x < 128) {
    // ---- weight synthesis for o = blockIdx.x ----
    u32*   wb  = (u32*)(ws + WB_OFF);
    float* Bf  = (float*)(ws + BF_OFF);
    float* n2a = (float*)(ws + N2A_OFF);
    __shared__ float sw[1152];
    __shared__ u32 sbits[36];
    __shared__ int spc[9];
    int o = blockIdx.x;
    float r0 = rv[0], r1 = rv[1], r2 = rv[2], r3 = rv[3], r4 = rv[4];
    const float4* M4 = (const float4*)M;
    const float4* Z4 = (const float4*)Z;
    float4* sw4 = (float4*)sw;

    for (int j = t; j < 288; j += 256) {
      float4 a = M4[o * 288 + j];
      float4 z;
      z = Z4[0 * 36864 + o * 288 + j];
      a.x = fmaf(r0, z.x, a.x); a.y = fmaf(r0, z.y, a.y);
      a.z = fmaf(r0, z.z, a.z); a.w = fmaf(r0, z.w, a.w);
      z = Z4[1 * 36864 + o * 288 + j];
      a.x = fmaf(r1, z.x, a.x); a.y = fmaf(r1, z.y, a.y);
      a.z = fmaf(r1, z.z, a.z); a.w = fmaf(r1, z.w, a.w);
      z = Z4[2 * 36864 + o * 288 + j];
      a.x = fmaf(r2, z.x, a.x); a.y = fmaf(r2, z.y, a.y);
      a.z = fmaf(r2, z.z, a.z); a.w = fmaf(r2, z.w, a.w);
      z = Z4[3 * 36864 + o * 288 + j];
      a.x = fmaf(r3, z.x, a.x); a.y = fmaf(r3, z.y, a.y);
      a.z = fmaf(r3, z.z, a.z); a.w = fmaf(r3, z.w, a.w);
      z = Z4[4 * 36864 + o * 288 + j];
      a.x = fmaf(r4, z.x, a.x); a.y = fmaf(r4, z.y, a.y);
      a.z = fmaf(r4, z.z, a.z); a.w = fmaf(r4, z.w, a.w);
      sw4[j] = a;
    }
    __syncthreads();

    if (t < 36) {                       // t = tap*4 + word
      int tap = t >> 2;
      int wd  = t & 3;
      u32 bits = 0;
#pragma unroll
      for (int c = 0; c < 32; ++c) {
        float v = sw[(wd * 32 + c) * 9 + tap];
        bits |= (v > 0.0f ? 1u : 0u) << c;
      }
      wb[(o * 9 + tap) * 4 + wd] = bits;
      sbits[t] = bits;
    }
    __syncthreads();
    if (t < 9)
      spc[t] = __popc(sbits[4 * t]) + __popc(sbits[4 * t + 1])
             + __popc(sbits[4 * t + 2]) + __popc(sbits[4 * t + 3]);
    __syncthreads();
    if (t < 9) {                        // t = edge class ht*3+wt
      int ht = t / 3, wt = t - ht * 3;
      int corr = 0;
#pragma unroll
      for (int tap = 0; tap < 9; ++tap) {
        int dh = tap / 3, dw = tap - dh * 3;
        int inv = ((ht == 0) & (dh == 0)) | ((ht == 2) & (dh == 2)) |
                  ((wt == 0) & (dw == 0)) | ((wt == 2) & (dw == 2));
        if (inv) corr += 128 - 2 * spc[tap];
      }
      Bf[t * 128 + o] = (float)(1152 - corr) * Alpha[o];
    }
    if (t == 0) n2a[o] = -2.0f * Alpha[o];
  } else {
    // ---- activation sign-pack (writes its own zero ring) ----
    u32* abw  = (u32*)(ws + AB_OFF);
    int bidx  = blockIdx.x - 128;
    int chunk = bidx % 53;              // 53*64 = 3392 >= 3364
    int b     = bidx / 53;
    int px    = chunk * 64 + (t & 63);
    int g     = t >> 6;
    if (px >= PADHW) return;
    int ph = px / PADW;
    int pw = px - ph * PADW;
    u32 bits = 0;
    if (ph >= 1 && ph <= 56 && pw >= 1 && pw <= 56) {
      const float* xp = x + (size_t)b * (128 * HW) + (size_t)g * (32 * HW)
                          + (ph - 1) * 56 + (pw - 1);
#pragma unroll
      for (int c = 0; c < 32; ++c)
        bits |= (xp[(size_t)c * HW] > 0.0f ? 1u : 0u) << c;
    }
    abw[((size_t)b * PADHW + px) * 4 + g] = bits;
  }
}

// ---------------------------------------------------------------------------
// Conv: uniform for ALL pixels (ring-zero + correction table replaces edge
// masking). Thread = 4 w-consecutive pixels (aligned quad), 8 o's.
// Grid: 16 og * 98 blocks, 98*256 = 25088 = 32*56*14 quads exactly.
// s = unmasked 9-tap popc; out = fmaf(s, -2a[o], Bf[class][o]).
__global__ __launch_bounds__(256) void k_conv(
    const char* __restrict__ ws, float* __restrict__ out)
{
  const uint4*  ab  = (const uint4*)(ws + AB_OFF);
  const uint4*  wbg = (const uint4*)(ws + WB_OFF);
  const float*  BfG = (const float*)(ws + BF_OFF);
  const float*  n2a = (const float*)(ws + N2A_OFF);

  __shared__ float sBf[9][8];
  int tid = threadIdx.x;
  int bx  = blockIdx.x;
  int og  = bx / 98;                    // uniform per block
  int o0  = og * 8;
  if (tid < 72) {
    int cl = tid / 8, oi = tid - cl * 8;
    sBf[cl][oi] = BfG[cl * 128 + o0 + oi];
  }
  __syncthreads();

  int q  = (bx - og * 98) * 256 + tid;  // 0..25087
  int b  = q / 784;
  int r  = q - b * 784;
  int h  = r / 14;
  int w4 = r - h * 14;
  int w0 = w4 * 4;

  // taps: padded rows h..h+2, cols w0..w0+5
  const uint4* ap = ab + ((size_t)b * PADW + h) * PADW + w0;
  u32 A[3][6][4];
#pragma unroll
  for (int rr = 0; rr < 3; ++rr)
#pragma unroll
    for (int cc = 0; cc < 6; ++cc) {
      uint4 v = ap[(size_t)rr * PADW + cc];
      A[rr][cc][0] = v.x; A[rr][cc][1] = v.y;
      A[rr][cc][2] = v.z; A[rr][cc][3] = v.w;
    }

  int ht  = (h == 0) ? 0 : (h == 55 ? 6 : 3);
  int cl0 = ht + ((w0 == 0) ? 0 : 1);
  int cl1 = ht + 1;
  int cl3 = ht + ((w0 == 52) ? 2 : 1);

  float* outp = out + ((size_t)b * 128 + o0) * HW + h * 56 + w0;

#pragma unroll
  for (int oi = 0; oi < 8; ++oi) {
    int o = o0 + oi;
    int s0 = 0, s1 = 0, s2 = 0, s3 = 0;
#pragma unroll
    for (int dh = 0; dh < 3; ++dh)
#pragma unroll
      for (int dw = 0; dw < 3; ++dw) {
        uint4 wv = wbg[o * 9 + dh * 3 + dw];
#pragma unroll
        for (int k = 0; k < 4; ++k) {
          u32 wk = (&wv.x)[k];
          s0 += __popc(A[dh][dw + 0][k] ^ wk);
          s1 += __popc(A[dh][dw + 1][k] ^ wk);
          s2 += __popc(A[dh][dw + 2][k] ^ wk);
          s3 += __popc(A[dh][dw + 3][k] ^ wk);
        }
      }
    float na = n2a[o];
    float4 ov;
    ov.x = fmaf((float)s0, na, sBf[0][oi] + (sBf[cl0][oi] - sBf[0][oi]));
    // (single LDS read per px; written plainly below)
    ov.x = fmaf((float)s0, na, sBf[cl0][oi]);
    ov.y = fmaf((float)s1, na, sBf[cl1][oi]);
    ov.z = fmaf((float)s2, na, sBf[cl1][oi]);
    ov.w = fmaf((float)s3, na, sBf[cl3][oi]);
    *(float4*)(outp + (size_t)oi * HW) = ov;
  }
}

// ---------------------------------------------------------------------------
extern "C" void kernel_launch(void* const* d_in, const int* in_sizes, int n_in,
                              void* d_out, int out_size, void* d_ws, size_t ws_size,
                              hipStream_t stream)
{
  const float* x     = (const float*)d_in[0];
  const float* Alpha = (const float*)d_in[1];
  const float* M     = (const float*)d_in[2];
  const float* Z     = (const float*)d_in[3];
  const float* rv    = (const float*)d_in[4];
  float* out         = (float*)d_out;
  char*  ws          = (char*)d_ws;

  k_prep<<<128 + 32 * 53, 256, 0, stream>>>(x, Alpha, M, Z, rv, ws);
  k_conv<<<16 * 98, 256, 0, stream>>>(ws, out);
}

// Round 5
// 135.138 us; speedup vs baseline: 1.9240x; 1.0097x over previous
//
#include <hip/hip_runtime.h>
#include <stdint.h>

typedef unsigned int u32;
typedef unsigned long long u64;

#define HW      3136     // 56*56
#define PADW    58
#define PADHW   3364     // 58*58

// d_ws layout
#define WB_OFF   0        // 4608 u32  (18432 B)  packed weights
#define BF_OFF   18432    // 9*128 f32 (4608 B)   per-(class,o) base, alpha-folded
#define N2A_OFF  23040    // 128 f32   (512 B)    -2*alpha
#define AB_OFF   23552    // 32*3364 uint4        padded activation bits

// prep grid split
#define NB_W     128      // weight-synthesis blocks (one per o)
#define NB_A     392      // apack interior: 32 b * 4 g * 784 quads / 256
#define NB_R     29       // ring-zero: 32 b * 228 ring px -> 7296 uint4 / 256

// ---------------------------------------------------------------------------
// Prep kernel, 3 block classes.
// [0,128):   weight synthesis + sign-pack + correction tables.
//            sign(w) = sign(m + rv.z) (rsqrt normalizer is positive).
// [128,520): activation sign-pack, float4-vectorized: thread = (b,g,quad),
//            32 coalesced float4 reads, 4 bit-words assembled in regs.
// [520,549): zero the 58x58 ring (228 px/image) so border taps read 0.
__global__ __launch_bounds__(256) void k_prep(
    const float* __restrict__ x, const float* __restrict__ Alpha,
    const float* __restrict__ M, const float* __restrict__ Z,
    const float* __restrict__ rv, char* __restrict__ ws)
{
  int t = threadIdx.x;
  if (blockIdx.x < NB_W) {
    // ---- weight synthesis for o = blockIdx.x ----
    u32*   wb  = (u32*)(ws + WB_OFF);
    float* Bf  = (float*)(ws + BF_OFF);
    float* n2a = (float*)(ws + N2A_OFF);
    __shared__ float sw[1152];
    __shared__ u32 sbits[36];
    __shared__ int spc[9];
    int o = blockIdx.x;
    float r0 = rv[0], r1 = rv[1], r2 = rv[2], r3 = rv[3], r4 = rv[4];
    const float4* M4 = (const float4*)M;
    const float4* Z4 = (const float4*)Z;
    float4* sw4 = (float4*)sw;

    for (int j = t; j < 288; j += 256) {
      float4 a = M4[o * 288 + j];
      float4 z;
      z = Z4[0 * 36864 + o * 288 + j];
      a.x = fmaf(r0, z.x, a.x); a.y = fmaf(r0, z.y, a.y);
      a.z = fmaf(r0, z.z, a.z); a.w = fmaf(r0, z.w, a.w);
      z = Z4[1 * 36864 + o * 288 + j];
      a.x = fmaf(r1, z.x, a.x); a.y = fmaf(r1, z.y, a.y);
      a.z = fmaf(r1, z.z, a.z); a.w = fmaf(r1, z.w, a.w);
      z = Z4[2 * 36864 + o * 288 + j];
      a.x = fmaf(r2, z.x, a.x); a.y = fmaf(r2, z.y, a.y);
      a.z = fmaf(r2, z.z, a.z); a.w = fmaf(r2, z.w, a.w);
      z = Z4[3 * 36864 + o * 288 + j];
      a.x = fmaf(r3, z.x, a.x); a.y = fmaf(r3, z.y, a.y);
      a.z = fmaf(r3, z.z, a.z); a.w = fmaf(r3, z.w, a.w);
      z = Z4[4 * 36864 + o * 288 + j];
      a.x = fmaf(r4, z.x, a.x); a.y = fmaf(r4, z.y, a.y);
      a.z = fmaf(r4, z.z, a.z); a.w = fmaf(r4, z.w, a.w);
      sw4[j] = a;
    }
    __syncthreads();

    if (t < 36) {                       // t = tap*4 + word
      int tap = t >> 2;
      int wd  = t & 3;
      u32 bits = 0;
#pragma unroll
      for (int c = 0; c < 32; ++c) {
        float v = sw[(wd * 32 + c) * 9 + tap];
        bits |= (v > 0.0f ? 1u : 0u) << c;
      }
      wb[(o * 9 + tap) * 4 + wd] = bits;
      sbits[t] = bits;
    }
    __syncthreads();
    if (t < 9)
      spc[t] = __popc(sbits[4 * t]) + __popc(sbits[4 * t + 1])
             + __popc(sbits[4 * t + 2]) + __popc(sbits[4 * t + 3]);
    __syncthreads();
    if (t < 9) {                        // t = edge class ht*3+wt
      int ht = t / 3, wt = t - ht * 3;
      int corr = 0;
#pragma unroll
      for (int tap = 0; tap < 9; ++tap) {
        int dh = tap / 3, dw = tap - dh * 3;
        int inv = ((ht == 0) & (dh == 0)) | ((ht == 2) & (dh == 2)) |
                  ((wt == 0) & (dw == 0)) | ((wt == 2) & (dw == 2));
        if (inv) corr += 128 - 2 * spc[tap];
      }
      Bf[t * 128 + o] = (float)(1152 - corr) * Alpha[o];
    }
    if (t == 0) n2a[o] = -2.0f * Alpha[o];
  } else if (blockIdx.x < NB_W + NB_A) {
    // ---- activation sign-pack, vectorized ----
    u32* abw = (u32*)(ws + AB_OFF);
    int idx = (blockIdx.x - NB_W) * 256 + t;  // (b*4+g)*784 + q
    int bg  = idx / 784;
    int q   = idx - bg * 784;                 // pixel quad 0..783
    int b   = bg >> 2;
    int g   = bg & 3;
    int h   = q / 14;                         // 4 | 56 -> no row wrap in quad
    int w0  = (q - h * 14) * 4;

    const float4* X4 = (const float4*)x
        + ((size_t)b * 128 + g * 32) * (HW / 4) + q;
    u32 m0 = 0, m1 = 0, m2 = 0, m3 = 0;
#pragma unroll
    for (int c = 0; c < 32; ++c) {
      float4 f = X4[(size_t)c * (HW / 4)];
      m0 |= (f.x > 0.0f ? 1u : 0u) << c;
      m1 |= (f.y > 0.0f ? 1u : 0u) << c;
      m2 |= (f.z > 0.0f ? 1u : 0u) << c;
      m3 |= (f.w > 0.0f ? 1u : 0u) << c;
    }
    size_t base = ((size_t)b * PADHW + (h + 1) * PADW + (w0 + 1)) * 4 + g;
    abw[base]      = m0;
    abw[base + 4]  = m1;
    abw[base + 8]  = m2;
    abw[base + 12] = m3;
  } else {
    // ---- ring zero ----
    uint4* ab4 = (uint4*)(ws + AB_OFF);
    int e = (blockIdx.x - NB_W - NB_A) * 256 + t;
    if (e >= 32 * 228) return;
    int b  = e / 228;
    int r  = e - b * 228;
    int pp;
    if      (r < 58)  pp = r;                       // top row
    else if (r < 116) pp = 57 * PADW + (r - 58);    // bottom row
    else {                                          // sides
      int s = r - 116;
      pp = (1 + (s >> 1)) * PADW + ((s & 1) ? 57 : 0);
    }
    ab4[(size_t)b * PADHW + pp] = make_uint4(0, 0, 0, 0);
  }
}

// ---------------------------------------------------------------------------
// Conv: uniform for ALL pixels (zero ring + correction table replaces edge
// masking). Thread = 4 w-consecutive pixels (aligned quad), 8 o's.
// Grid (98, 16): 98*256 = 25088 = 32*784 quads exactly; blockIdx.y = og.
// s = unmasked 9-tap popc; out = fmaf(s, -2a[o], Bf[class][o]).
__global__ __launch_bounds__(256) void k_conv(
    const char* __restrict__ ws, float* __restrict__ out)
{
  const uint4*  ab  = (const uint4*)(ws + AB_OFF);
  const uint4*  wbg = (const uint4*)(ws + WB_OFF);
  const float*  BfG = (const float*)(ws + BF_OFF);
  const float*  n2a = (const float*)(ws + N2A_OFF);

  __shared__ float sBf[9][8];
  int tid = threadIdx.x;
  int og  = blockIdx.y;
  int o0  = og * 8;
  if (tid < 72) {
    int cl = tid / 8, oi = tid - cl * 8;
    sBf[cl][oi] = BfG[cl * 128 + o0 + oi];
  }
  __syncthreads();

  int q  = blockIdx.x * 256 + tid;      // 0..25087
  int b  = q / 784;
  int r  = q - b * 784;
  int h  = r / 14;
  int w4 = r - h * 14;
  int w0 = w4 * 4;

  // taps: padded rows h..h+2, cols w0..w0+5
  const uint4* ap = ab + ((size_t)b * PADW + h) * PADW + w0;
  u32 A[3][6][4];
#pragma unroll
  for (int rr = 0; rr < 3; ++rr)
#pragma unroll
    for (int cc = 0; cc < 6; ++cc) {
      uint4 v = ap[(size_t)rr * PADW + cc];
      A[rr][cc][0] = v.x; A[rr][cc][1] = v.y;
      A[rr][cc][2] = v.z; A[rr][cc][3] = v.w;
    }

  int ht  = (h == 0) ? 0 : (h == 55 ? 6 : 3);
  int cl0 = ht + ((w0 == 0) ? 0 : 1);
  int cl1 = ht + 1;
  int cl3 = ht + ((w0 == 52) ? 2 : 1);

  float* outp = out + ((size_t)b * 128 + o0) * HW + h * 56 + w0;

#pragma unroll
  for (int oi = 0; oi < 8; ++oi) {
    int o = o0 + oi;
    int s0 = 0, s1 = 0, s2 = 0, s3 = 0;
#pragma unroll
    for (int dh = 0; dh < 3; ++dh)
#pragma unroll
      for (int dw = 0; dw < 3; ++dw) {
        uint4 wv = wbg[o * 9 + dh * 3 + dw];
#pragma unroll
        for (int k = 0; k < 4; ++k) {
          u32 wk = (&wv.x)[k];
          s0 += __popc(A[dh][dw + 0][k] ^ wk);
          s1 += __popc(A[dh][dw + 1][k] ^ wk);
          s2 += __popc(A[dh][dw + 2][k] ^ wk);
          s3 += __popc(A[dh][dw + 3][k] ^ wk);
        }
      }
    float na = n2a[o];
    float4 ov;
    ov.x = fmaf((float)s0, na, sBf[cl0][oi]);
    ov.y = fmaf((float)s1, na, sBf[cl1][oi]);
    ov.z = fmaf((float)s2, na, sBf[cl1][oi]);
    ov.w = fmaf((float)s3, na, sBf[cl3][oi]);
    *(float4*)(outp + (size_t)oi * HW) = ov;
  }
}

// ---------------------------------------------------------------------------
extern "C" void kernel_launch(void* const* d_in, const int* in_sizes, int n_in,
                              void* d_out, int out_size, void* d_ws, size_t ws_size,
                              hipStream_t stream)
{
  const float* x     = (const float*)d_in[0];
  const float* Alpha = (const float*)d_in[1];
  const float* M     = (const float*)d_in[2];
  const float* Z     = (const float*)d_in[3];
  const float* rv    = (const float*)d_in[4];
  float* out         = (float*)d_out;
  char*  ws          = (char*)d_ws;

  k_prep<<<NB_W + NB_A + NB_R, 256, 0, stream>>>(x, Alpha, M, Z, rv, ws);
  k_conv<<<dim3(98, 16), 256, 0, stream>>>(ws, out);
}

// Round 6
// 134.111 us; speedup vs baseline: 1.9387x; 1.0077x over previous
//
#include <hip/hip_runtime.h>
#include <stdint.h>

typedef unsigned int u32;
typedef unsigned long long u64;

#define HW      3136     // 56*56
#define PADW    58
#define PADHW   3364     // 58*58

// d_ws layout
#define WB_OFF   0        // 4608 u32  (18432 B)  packed weights
#define BF_OFF   18432    // 9*128 f32 (4608 B)   per-(class,o) base, alpha-folded
#define N2A_OFF  23040    // 128 f32   (512 B)    -2*alpha
#define AB_OFF   23552    // 32*3364 uint4        padded activation bits

// prep grid split
#define NB_W     128      // weight-synthesis blocks (one per o)
#define NB_A     392      // apack interior: 32 b * 4 g * 784 quads / 256
#define NB_R     29       // ring-zero: 32 b * 228 ring px -> 7296 uint4 / 256

// ---------------------------------------------------------------------------
// Prep kernel, 3 block classes.
// [0,128):   weight synthesis + sign-pack + correction tables.
//            sign(w) = sign(m + rv.z) (rsqrt normalizer is positive).
// [128,520): activation sign-pack, float4-vectorized: thread = (b,g,quad),
//            32 coalesced float4 reads, 4 bit-words assembled in regs.
// [520,549): zero the 58x58 ring (228 px/image) so border taps read 0.
__global__ __launch_bounds__(256) void k_prep(
    const float* __restrict__ x, const float* __restrict__ Alpha,
    const float* __restrict__ M, const float* __restrict__ Z,
    const float* __restrict__ rv, char* __restrict__ ws)
{
  int t = threadIdx.x;
  if (blockIdx.x < NB_W) {
    // ---- weight synthesis for o = blockIdx.x ----
    u32*   wb  = (u32*)(ws + WB_OFF);
    float* Bf  = (float*)(ws + BF_OFF);
    float* n2a = (float*)(ws + N2A_OFF);
    __shared__ float sw[1152];
    __shared__ u32 sbits[36];
    __shared__ int spc[9];
    int o = blockIdx.x;
    float r0 = rv[0], r1 = rv[1], r2 = rv[2], r3 = rv[3], r4 = rv[4];
    const float4* M4 = (const float4*)M;
    const float4* Z4 = (const float4*)Z;
    float4* sw4 = (float4*)sw;

    for (int j = t; j < 288; j += 256) {
      float4 a = M4[o * 288 + j];
      float4 z;
      z = Z4[0 * 36864 + o * 288 + j];
      a.x = fmaf(r0, z.x, a.x); a.y = fmaf(r0, z.y, a.y);
      a.z = fmaf(r0, z.z, a.z); a.w = fmaf(r0, z.w, a.w);
      z = Z4[1 * 36864 + o * 288 + j];
      a.x = fmaf(r1, z.x, a.x); a.y = fmaf(r1, z.y, a.y);
      a.z = fmaf(r1, z.z, a.z); a.w = fmaf(r1, z.w, a.w);
      z = Z4[2 * 36864 + o * 288 + j];
      a.x = fmaf(r2, z.x, a.x); a.y = fmaf(r2, z.y, a.y);
      a.z = fmaf(r2, z.z, a.z); a.w = fmaf(r2, z.w, a.w);
      z = Z4[3 * 36864 + o * 288 + j];
      a.x = fmaf(r3, z.x, a.x); a.y = fmaf(r3, z.y, a.y);
      a.z = fmaf(r3, z.z, a.z); a.w = fmaf(r3, z.w, a.w);
      z = Z4[4 * 36864 + o * 288 + j];
      a.x = fmaf(r4, z.x, a.x); a.y = fmaf(r4, z.y, a.y);
      a.z = fmaf(r4, z.z, a.z); a.w = fmaf(r4, z.w, a.w);
      sw4[j] = a;
    }
    __syncthreads();

    if (t < 36) {                       // t = tap*4 + word
      int tap = t >> 2;
      int wd  = t & 3;
      u32 bits = 0;
#pragma unroll
      for (int c = 0; c < 32; ++c) {
        float v = sw[(wd * 32 + c) * 9 + tap];
        bits |= (v > 0.0f ? 1u : 0u) << c;
      }
      wb[(o * 9 + tap) * 4 + wd] = bits;
      sbits[t] = bits;
    }
    __syncthreads();
    if (t < 9)
      spc[t] = __popc(sbits[4 * t]) + __popc(sbits[4 * t + 1])
             + __popc(sbits[4 * t + 2]) + __popc(sbits[4 * t + 3]);
    __syncthreads();
    if (t < 9) {                        // t = edge class ht*3+wt
      int ht = t / 3, wt = t - ht * 3;
      int corr = 0;
#pragma unroll
      for (int tap = 0; tap < 9; ++tap) {
        int dh = tap / 3, dw = tap - dh * 3;
        int inv = ((ht == 0) & (dh == 0)) | ((ht == 2) & (dh == 2)) |
                  ((wt == 0) & (dw == 0)) | ((wt == 2) & (dw == 2));
        if (inv) corr += 128 - 2 * spc[tap];
      }
      Bf[t * 128 + o] = (float)(1152 - corr) * Alpha[o];
    }
    if (t == 0) n2a[o] = -2.0f * Alpha[o];
  } else if (blockIdx.x < NB_W + NB_A) {
    // ---- activation sign-pack, vectorized ----
    u32* abw = (u32*)(ws + AB_OFF);
    int idx = (blockIdx.x - NB_W) * 256 + t;  // (b*4+g)*784 + q
    int bg  = idx / 784;
    int q   = idx - bg * 784;                 // pixel quad 0..783
    int b   = bg >> 2;
    int g   = bg & 3;
    int h   = q / 14;                         // 4 | 56 -> no row wrap in quad
    int w0  = (q - h * 14) * 4;

    const float4* X4 = (const float4*)x
        + ((size_t)b * 128 + g * 32) * (HW / 4) + q;
    u32 m0 = 0, m1 = 0, m2 = 0, m3 = 0;
#pragma unroll
    for (int c = 0; c < 32; ++c) {
      float4 f = X4[(size_t)c * (HW / 4)];
      m0 |= (f.x > 0.0f ? 1u : 0u) << c;
      m1 |= (f.y > 0.0f ? 1u : 0u) << c;
      m2 |= (f.z > 0.0f ? 1u : 0u) << c;
      m3 |= (f.w > 0.0f ? 1u : 0u) << c;
    }
    size_t base = ((size_t)b * PADHW + (h + 1) * PADW + (w0 + 1)) * 4 + g;
    abw[base]      = m0;
    abw[base + 4]  = m1;
    abw[base + 8]  = m2;
    abw[base + 12] = m3;
  } else {
    // ---- ring zero ----
    uint4* ab4 = (uint4*)(ws + AB_OFF);
    int e = (blockIdx.x - NB_W - NB_A) * 256 + t;
    if (e >= 32 * 228) return;
    int b  = e / 228;
    int r  = e - b * 228;
    int pp;
    if      (r < 58)  pp = r;                       // top row
    else if (r < 116) pp = 57 * PADW + (r - 58);    // bottom row
    else {                                          // sides
      int s = r - 116;
      pp = (1 + (s >> 1)) * PADW + ((s & 1) ? 57 : 0);
    }
    ab4[(size_t)b * PADHW + pp] = make_uint4(0, 0, 0, 0);
  }
}

// ---------------------------------------------------------------------------
// Conv: uniform for ALL pixels (zero ring + correction table replaces edge
// masking). 64-thread blocks (fine-grained -> even CU load), thread = 4
// w-consecutive pixels (aligned quad), 8 o's. Grid (392, 16): 392*64 =
// 25088 = 32*784 quads exactly; blockIdx.y = og. Weights + Bf + n2a staged
// in LDS; inner-loop weight reads are uniform-address ds_read broadcasts.
// s = unmasked 9-tap popc; out = fmaf(s, -2a[o], Bf[class][o]).
__global__ __launch_bounds__(64) void k_conv(
    const char* __restrict__ ws, float* __restrict__ out)
{
  const uint4*  ab  = (const uint4*)(ws + AB_OFF);
  const uint4*  wbg = (const uint4*)(ws + WB_OFF);
  const float*  BfG = (const float*)(ws + BF_OFF);
  const float*  n2a = (const float*)(ws + N2A_OFF);

  __shared__ uint4 swb[72];        // 8 o x 9 taps
  __shared__ float sBf[9][8];      // class x o
  __shared__ float sn2a[8];
  int tid = threadIdx.x;           // 0..63
  int og  = blockIdx.y;
  int o0  = og * 8;
#pragma unroll
  for (int j = tid; j < 72; j += 64) {
    swb[j] = wbg[o0 * 9 + j];
    (&sBf[0][0])[j] = BfG[(j >> 3) * 128 + o0 + (j & 7)];
  }
  if (tid < 8) sn2a[tid] = n2a[o0 + tid];
  __syncthreads();

  int q  = blockIdx.x * 64 + tid;       // 0..25087
  int b  = q / 784;
  int r  = q - b * 784;
  int h  = r / 14;
  int w4 = r - h * 14;
  int w0 = w4 * 4;

  // taps: padded rows h..h+2, cols w0..w0+5
  const uint4* ap = ab + ((size_t)b * PADW + h) * PADW + w0;
  u32 A[3][6][4];
#pragma unroll
  for (int rr = 0; rr < 3; ++rr)
#pragma unroll
    for (int cc = 0; cc < 6; ++cc) {
      uint4 v = ap[(size_t)rr * PADW + cc];
      A[rr][cc][0] = v.x; A[rr][cc][1] = v.y;
      A[rr][cc][2] = v.z; A[rr][cc][3] = v.w;
    }

  int ht  = (h == 0) ? 0 : (h == 55 ? 6 : 3);
  int cl0 = ht + ((w0 == 0) ? 0 : 1);
  int cl1 = ht + 1;
  int cl3 = ht + ((w0 == 52) ? 2 : 1);

  float* outp = out + ((size_t)b * 128 + o0) * HW + h * 56 + w0;

#pragma unroll
  for (int oi = 0; oi < 8; ++oi) {
    int s0 = 0, s1 = 0, s2 = 0, s3 = 0;
#pragma unroll
    for (int dh = 0; dh < 3; ++dh)
#pragma unroll
      for (int dw = 0; dw < 3; ++dw) {
        uint4 wv = swb[oi * 9 + dh * 3 + dw];
#pragma unroll
        for (int k = 0; k < 4; ++k) {
          u32 wk = (&wv.x)[k];
          s0 += __popc(A[dh][dw + 0][k] ^ wk);
          s1 += __popc(A[dh][dw + 1][k] ^ wk);
          s2 += __popc(A[dh][dw + 2][k] ^ wk);
          s3 += __popc(A[dh][dw + 3][k] ^ wk);
        }
      }
    float na = sn2a[oi];
    float4 ov;
    ov.x = fmaf((float)s0, na, sBf[cl0][oi]);
    ov.y = fmaf((float)s1, na, sBf[cl1][oi]);
    ov.z = fmaf((float)s2, na, sBf[cl1][oi]);
    ov.w = fmaf((float)s3, na, sBf[cl3][oi]);
    *(float4*)(outp + (size_t)oi * HW) = ov;
  }
}

// ---------------------------------------------------------------------------
extern "C" void kernel_launch(void* const* d_in, const int* in_sizes, int n_in,
                              void* d_out, int out_size, void* d_ws, size_t ws_size,
                              hipStream_t stream)
{
  const float* x     = (const float*)d_in[0];
  const float* Alpha = (const float*)d_in[1];
  const float* M     = (const float*)d_in[2];
  const float* Z     = (const float*)d_in[3];
  const float* rv    = (const float*)d_in[4];
  float* out         = (float*)d_out;
  char*  ws          = (char*)d_ws;

  k_prep<<<NB_W + NB_A + NB_R, 256, 0, stream>>>(x, Alpha, M, Z, rv, ws);
  k_conv<<<dim3(392, 16), 64, 0, stream>>>(ws, out);
}